// Round 4
// baseline (192.703 us; speedup 1.0000x reference)
//
#include <hip/hip_runtime.h>

#define NV    10
#define DD    2048
#define TAPS  25
#define CHUNK 128
#define NCH   (DD / CHUNK)          // 16
#define F4PC  ((CHUNK * TAPS) / 4)  // 800 float4 per chunk
#define F4PW  (F4PC / 4)            // 200 float4 per wave
#define OB    64

typedef __attribute__((address_space(1))) const unsigned int gu32;
typedef __attribute__((address_space(3))) unsigned int lu32;

__device__ __forceinline__ float bsign(float v) {
    return (v > 0.0f) ? 1.0f : ((v < 0.0f) ? -1.0f : 0.0f);
}

// Stage one 128-channel chunk (3200 floats) of w[o] into LDS, linear layout.
// Each wave issues EXACTLY 4 global_load_lds instrs (3 full + 1 with lanes 0-7)
// -> uniform vmcnt accounting. Masked lanes don't write LDS (verified R3).
__device__ __forceinline__ void stage(const float* __restrict__ gsrc,
                                      float* lbase, int lane, int wv) {
    const int b4 = wv * F4PW;
    #pragma unroll
    for (int i = 0; i < 3; ++i) {
        __builtin_amdgcn_global_load_lds((gu32*)(gsrc + 4 * (b4 + i * 64 + lane)),
                                         (lu32*)(lbase + 4 * (b4 + i * 64)), 16, 0, 0);
    }
    if (lane < 8) {
        __builtin_amdgcn_global_load_lds((gu32*)(gsrc + 4 * (b4 + 192 + lane)),
                                         (lu32*)(lbase + 4 * (b4 + 192)), 16, 0, 0);
    }
}

// G[tap][n][o] = sum_c sign(values[n][c])*sign(w[o][c][tap]) via ballot+popcount.
// One block per o. Double-buffered LDS staging, counted vmcnt(4), raw barriers:
// next chunk's loads stay in flight across the compute phase (T3 2-phase).
__global__ __launch_bounds__(256) void g_kernel(
        const float* __restrict__ values,
        const float* __restrict__ w,
        float* __restrict__ G) {
    const int o    = blockIdx.x;
    const int t    = threadIdx.x;
    const int lane = t & 63;
    const int wv   = t >> 6;

    __shared__ float buf[2][CHUNK * TAPS];          // 2 x 12.8 KB
    __shared__ unsigned long long s_vnz[32 * NV];   // [g][n]: bank-spread for 10-lane reads
    __shared__ unsigned long long s_vng[32 * NV];

    const float* wo = w + (size_t)o * (DD * TAPS);

    // get HBM going first
    stage(wo, &buf[0][0], lane, wv);

    // value masks, computed per-block (values is 80 KB, L2-hot). Overlaps chunk-0 staging.
    for (int t2 = wv; t2 < 32 * NV; t2 += 4) {
        const int g = t2 / NV;
        const int n = t2 - g * NV;
        float f = values[n * DD + g * 64 + lane];
        unsigned long long nz = __ballot(f != 0.0f);
        unsigned long long ng = __ballot(f < 0.0f);
        if (lane == 0) { s_vnz[g * NV + n] = nz; s_vng[g * NV + n] = ng; }
    }

    int acc[7] = {0, 0, 0, 0, 0, 0, 0};   // lanes 0..9: acc[k] for (tap=wv+4k, n=lane)

    for (int ch = 0; ch < NCH; ++ch) {
        const int cur = ch & 1;
        if (ch + 1 < NCH) {
            stage(wo + (size_t)(ch + 1) * (CHUNK * TAPS), &buf[cur ^ 1][0], lane, wv);
            // wait until only the 4 just-issued (next-chunk) loads remain -> cur chunk landed
            asm volatile("s_waitcnt vmcnt(4)" ::: "memory");
        } else {
            asm volatile("s_waitcnt vmcnt(0)" ::: "memory");
        }
        __builtin_amdgcn_s_barrier();      // all waves: buf[cur] fully staged (also publishes masks at ch=0)

        const float* cb = &buf[cur][0];
        #pragma unroll
        for (int k = 0; k < 7; ++k) {
            const int tap = wv + 4 * k;    // wave 0: 7 taps, waves 1-3: 6 taps
            if (tap < TAPS) {
                #pragma unroll
                for (int sub = 0; sub < 2; ++sub) {
                    // stride-25-word LDS read: 2 lanes/bank = conflict-free
                    float f = cb[(sub * 64 + lane) * TAPS + tap];
                    unsigned long long wnz = __ballot(f != 0.0f);
                    unsigned long long wng = __ballot(f < 0.0f);   // wave-uniform results
                    if (lane < NV) {
                        const int g = ch * 2 + sub;
                        unsigned long long vz  = s_vnz[g * NV + lane];
                        unsigned long long vg  = s_vng[g * NV + lane];
                        unsigned long long nzb = wnz & vz;
                        // exact: S += popc(bothnz) - 2*popc(signdiff & bothnz), zeros handled
                        acc[k] += (int)__popcll(nzb) - 2 * (int)__popcll((wng ^ vg) & nzb);
                    }
                }
            }
        }
        // pin ds_reads before the barrier, then allow next iter to overwrite buf[cur^1... (=buf[ch&1])
        asm volatile("s_waitcnt lgkmcnt(0)" ::: "memory");
        __builtin_amdgcn_s_barrier();
    }

    #pragma unroll
    for (int k = 0; k < 7; ++k) {
        const int tap = wv + 4 * k;
        if (tap < TAPS && lane < NV) {
            G[((size_t)(tap * NV + lane) << 11) + o] = (float)acc[k];
        }
    }
}

// out[b,o,oh,ow] = sign(sum_tap G[idx(tap)][o][tap] + bias[o])
// tap-sum is an exact integer in f32; bias added ONCE at the end (bit-exact sign).
// Grid 1024: (b, 64-o strip, position-half) -> 4 blocks/CU for latency hiding.
__global__ __launch_bounds__(256) void out_kernel(
        const float* __restrict__ x,
        const float* __restrict__ G,
        const float* __restrict__ bias,
        float* __restrict__ out) {
    const int bb    = blockIdx.x;
    const int half  = bb & 1;
    const int bq    = bb >> 1;
    const int b     = bq >> 5;
    const int oc    = bq & 31;
    const int obase = oc * OB;
    const int t     = threadIdx.x;

    __shared__ int   s_idx[28 * 28];
    __shared__ float s_out[OB * 73];     // [o_l][pos_local], odd stride: conflict-free

    for (int e = t; e < 28 * 28; e += 256) {
        s_idx[e] = (int)(x[b * 784 + e] * 9.0f);   // trunc, matches .astype(int32)
    }
    __syncthreads();

    const int o_l = t & (OB - 1);
    const int pg  = t >> 6;
    const float bv = bias[obase + o_l];
    const float* Gb = G + obase + o_l;

    for (int p0 = 0; p0 < 72; p0 += 4) {
        const int pos = half * 72 + p0 + pg;
        const int oh  = pos / 12;
        const int ow  = pos - oh * 12;
        float acc = 0.0f;                              // integer-exact accumulation
        #pragma unroll
        for (int kh = 0; kh < 5; ++kh) {
            const int row = (oh * 2 + kh) * 28 + ow * 2;
            #pragma unroll
            for (int kw = 0; kw < 5; ++kw) {
                const int nn = s_idx[row + kw];            // wave-uniform broadcast
                const int tp = kh * 5 + kw;
                acc += Gb[(size_t)(tp * NV + nn) << 11];   // coalesced, L2-hit
            }
        }
        s_out[o_l * 73 + p0 + pg] = bsign(acc + bv);
    }
    __syncthreads();

    float* dst = out + ((size_t)(b * DD + obase)) * 144;
    for (int e = t; e < OB * 72; e += 256) {
        const int ol = e / 72;
        const int pp = e - ol * 72;
        dst[ol * 144 + half * 72 + pp] = s_out[ol * 73 + pp];
    }
}

extern "C" void kernel_launch(void* const* d_in, const int* in_sizes, int n_in,
                              void* d_out, int out_size, void* d_ws, size_t ws_size,
                              hipStream_t stream) {
    const float* x      = (const float*)d_in[0];   // [16,1,28,28]
    const float* values = (const float*)d_in[1];   // [10,2048]
    const float* w      = (const float*)d_in[2];   // [2048,2048,5,5] OIHW
    const float* bias   = (const float*)d_in[3];   // [2048]
    float* out = (float*)d_out;                    // [16,2048,12,12]
    float* G   = (float*)d_ws;                     // 25*10*2048 floats = 2 MB scratch

    hipLaunchKernelGGL(g_kernel, dim3(DD), dim3(256), 0, stream, values, w, G);
    hipLaunchKernelGGL(out_kernel, dim3(16 * (DD / OB) * 2), dim3(256), 0, stream, x, G, bias, out);
}

// Round 5
// 159.910 us; speedup vs baseline: 1.2051x; 1.2051x over previous
//
#include <hip/hip_runtime.h>

#define NV   10
#define DD   2048
#define TAPS 25
#define OB   64

// 16B vector load with only 4B alignment guaranteed (w rows are 100B apart).
typedef float float4u __attribute__((ext_vector_type(4), aligned(4)));

__device__ __forceinline__ float bsign(float v) {
    return (v > 0.0f) ? 1.0f : ((v < 0.0f) ? -1.0f : 0.0f);
}

// G[tap][n][o] = sum_c sign(values[n][c])*sign(w[o][c][tap])  via ballot+popcount.
// One block per o. NO w-staging, NO per-chunk barriers: each lane owns channel
// c = g*64+lane and reads its 25-tap row straight into registers (memcpy regime:
// independent waves, pure TLP — every byte of each 6.4KB wave-region is consumed).
__global__ __launch_bounds__(256) void g_kernel(
        const float* __restrict__ values,
        const float* __restrict__ w,
        float* __restrict__ G) {
    const int o    = blockIdx.x;
    const int t    = threadIdx.x;
    const int lane = t & 63;
    const int wv   = t >> 6;

    __shared__ unsigned long long s_vnz[32 * NV];   // [g][n]
    __shared__ unsigned long long s_vng[32 * NV];
    __shared__ int s_g[TAPS * NV];

    // value sign/nonzero masks (values = 80KB, L2-hot). 320 (g,n) ballots.
    for (int t2 = wv; t2 < 32 * NV; t2 += 4) {      // t2 wave-uniform
        const int g = t2 / NV;
        const int n = t2 - g * NV;
        float f = values[n * DD + g * 64 + lane];
        unsigned long long nz = __ballot(f != 0.0f);
        unsigned long long ng = __ballot(f < 0.0f);
        if (lane == 0) { s_vnz[g * NV + n] = nz; s_vng[g * NV + n] = ng; }
    }
    for (int e = t; e < TAPS * NV; e += 256) s_g[e] = 0;
    __syncthreads();

    int acc[TAPS];
    #pragma unroll
    for (int i = 0; i < TAPS; ++i) acc[i] = 0;

    const float* wo = w + (size_t)o * (DD * TAPS);

    for (int g = wv; g < 32; g += 4) {              // 8 channel-groups per wave
        const float* row = wo + (size_t)(g * 64 + lane) * TAPS;
        // 25 floats = 6 x float4 (align-4) + 1 scalar; no overrun (24+1 = 25).
        float4u v0 = *(const float4u*)(row);
        float4u v1 = *(const float4u*)(row + 4);
        float4u v2 = *(const float4u*)(row + 8);
        float4u v3 = *(const float4u*)(row + 12);
        float4u v4 = *(const float4u*)(row + 16);
        float4u v5 = *(const float4u*)(row + 20);
        float   f24 = row[24];

        // per-(g,n) value masks live in lanes 0..9 (0 elsewhere -> acc unchanged)
        unsigned long long vz = 0ull, vg = 0ull;
        if (lane < NV) {
            vz = s_vnz[g * NV + lane];
            vg = s_vng[g * NV + lane];
        }

        // exact: S += popc(bothnz) - 2*popc(signdiff & bothnz); zeros handled.
        #define DO_TAP(T, F) {                                          \
            unsigned long long wng = __ballot((F) <  0.0f);             \
            unsigned long long wnz = __ballot((F) != 0.0f);             \
            unsigned long long nzb = wnz & vz;                          \
            acc[T] += (int)__popcll(nzb) - 2 * (int)__popcll((wng ^ vg) & nzb); }
        DO_TAP(0,  v0.x) DO_TAP(1,  v0.y) DO_TAP(2,  v0.z) DO_TAP(3,  v0.w)
        DO_TAP(4,  v1.x) DO_TAP(5,  v1.y) DO_TAP(6,  v1.z) DO_TAP(7,  v1.w)
        DO_TAP(8,  v2.x) DO_TAP(9,  v2.y) DO_TAP(10, v2.z) DO_TAP(11, v2.w)
        DO_TAP(12, v3.x) DO_TAP(13, v3.y) DO_TAP(14, v3.z) DO_TAP(15, v3.w)
        DO_TAP(16, v4.x) DO_TAP(17, v4.y) DO_TAP(18, v4.z) DO_TAP(19, v4.w)
        DO_TAP(20, v5.x) DO_TAP(21, v5.y) DO_TAP(22, v5.z) DO_TAP(23, v5.w)
        DO_TAP(24, f24)
        #undef DO_TAP
    }

    // cross-wave combine: exact integer LDS atomics (order-independent).
    #pragma unroll
    for (int tp = 0; tp < TAPS; ++tp) {
        if (lane < NV) atomicAdd(&s_g[tp * NV + lane], acc[tp]);
    }
    __syncthreads();

    for (int e = t; e < TAPS * NV; e += 256) {
        G[((size_t)e << 11) + o] = (float)s_g[e];   // G[tap][n][o]
    }
}

// out[b,o,oh,ow] = sign(sum_tap G[idx(tap)][o][tap] + bias[o])
// tap-sum is an exact integer in f32; bias added ONCE at the end (bit-exact sign).
__global__ __launch_bounds__(256) void out_kernel(
        const float* __restrict__ x,
        const float* __restrict__ G,
        const float* __restrict__ bias,
        float* __restrict__ out) {
    const int bb    = blockIdx.x;
    const int half  = bb & 1;
    const int bq    = bb >> 1;
    const int b     = bq >> 5;
    const int oc    = bq & 31;
    const int obase = oc * OB;
    const int t     = threadIdx.x;

    __shared__ int   s_idx[28 * 28];
    __shared__ float s_out[OB * 73];     // [o_l][pos_local], odd stride: conflict-free

    for (int e = t; e < 28 * 28; e += 256) {
        s_idx[e] = (int)(x[b * 784 + e] * 9.0f);   // trunc, matches .astype(int32)
    }
    __syncthreads();

    const int o_l = t & (OB - 1);
    const int pg  = t >> 6;
    const float bv = bias[obase + o_l];
    const float* Gb = G + obase + o_l;

    for (int p0 = 0; p0 < 72; p0 += 4) {
        const int pos = half * 72 + p0 + pg;
        const int oh  = pos / 12;
        const int ow  = pos - oh * 12;
        float acc = 0.0f;                              // integer-exact accumulation
        #pragma unroll
        for (int kh = 0; kh < 5; ++kh) {
            const int row = (oh * 2 + kh) * 28 + ow * 2;
            #pragma unroll
            for (int kw = 0; kw < 5; ++kw) {
                const int nn = s_idx[row + kw];            // wave-uniform broadcast
                const int tp = kh * 5 + kw;
                acc += Gb[(size_t)(tp * NV + nn) << 11];   // coalesced, L2-hit
            }
        }
        s_out[o_l * 73 + p0 + pg] = bsign(acc + bv);
    }
    __syncthreads();

    float* dst = out + ((size_t)(b * DD + obase)) * 144;
    for (int e = t; e < OB * 72; e += 256) {
        const int ol = e / 72;
        const int pp = e - ol * 72;
        dst[ol * 144 + half * 72 + pp] = s_out[ol * 73 + pp];
    }
}

extern "C" void kernel_launch(void* const* d_in, const int* in_sizes, int n_in,
                              void* d_out, int out_size, void* d_ws, size_t ws_size,
                              hipStream_t stream) {
    const float* x      = (const float*)d_in[0];   // [16,1,28,28]
    const float* values = (const float*)d_in[1];   // [10,2048]
    const float* w      = (const float*)d_in[2];   // [2048,2048,5,5] OIHW
    const float* bias   = (const float*)d_in[3];   // [2048]
    float* out = (float*)d_out;                    // [16,2048,12,12]
    float* G   = (float*)d_ws;                     // 25*10*2048 floats = 2 MB scratch

    hipLaunchKernelGGL(g_kernel, dim3(DD), dim3(256), 0, stream, values, w, G);
    hipLaunchKernelGGL(out_kernel, dim3(16 * (DD / OB) * 2), dim3(256), 0, stream, x, G, bias, out);
}